// Round 14
// baseline (460.437 us; speedup 1.0000x reference)
//
#include <hip/hip_runtime.h>
#include <hip/hip_bf16.h>
#include <math.h>

typedef __bf16 bf16x8 __attribute__((ext_vector_type(8)));
typedef __bf16 bf16x4 __attribute__((ext_vector_type(4)));
typedef float f32x4 __attribute__((ext_vector_type(4)));

#define DEVI __device__ __forceinline__

// async global->LDS DMA, 16B per lane. LDS dest is wave-uniform base + lane*16.
DEVI void gload_lds16(const __bf16* g, __bf16* l) {
    __builtin_amdgcn_global_load_lds(
        (const __attribute__((address_space(1))) unsigned int*)g,
        (__attribute__((address_space(3))) unsigned int*)l, 16, 0, 0);
}

// Abramowitz-Stegun 7.1.26 erf: |err| <= 1.5e-7, branch-free.
DEVI float fast_erf(float x) {
    const float ax = __builtin_fabsf(x);
    const float t = __builtin_amdgcn_rcpf(__builtin_fmaf(0.3275911f, ax, 1.0f));
    float p = __builtin_fmaf(1.061405429f, t, -1.453152027f);
    p = __builtin_fmaf(p, t, 1.421413741f);
    p = __builtin_fmaf(p, t, -0.284496736f);
    p = __builtin_fmaf(p, t, 0.254829592f);
    const float e = __expf(-ax * ax);
    const float r = __builtin_fmaf(-p * t, e, 1.0f);
    return __builtin_copysignf(r, x);
}

DEVI float gelu_exact(float v) {
    return 0.5f * v * (1.0f + fast_erf(v * 0.70710678118654752f));
}

// XOR swizzle for [rows][128] bf16 LDS tiles read column-slice-wise.
DEVI int swz128(int row, int col) { return row * 128 + (col ^ ((row & 7) << 3)); }

// ---------------------------------------------------------------------------
// dtype sniffer (tri-modal). flag[0]=1 -> inputs are fp32 storage.
__global__ void sniff_kernel(const unsigned short* __restrict__ x, int* flags) {
    const int tid = threadIdx.x;  // 256
    const unsigned short u = x[tid * 2];
    const int e = (u >> 7) & 0xFF;
    const int zero = (u == 0) ? 1 : 0;
    const int sane = ((e >= 0x71 && e <= 0x8E) || ((u & 0x7FFF) == 0)) ? 1 : 0;
    const unsigned long long mz = __ballot(zero != 0);
    const unsigned long long ms = __ballot(sane != 0);
    __shared__ int wz[4], wsn[4];
    if ((tid & 63) == 0) { wz[tid >> 6] = __popcll(mz); wsn[tid >> 6] = __popcll(ms); }
    __syncthreads();
    if (tid == 0) {
        const int nz = wz[0] + wz[1] + wz[2] + wz[3];
        const int ns = wsn[0] + wsn[1] + wsn[2] + wsn[3];
        flags[0] = (nz >= 192 || ns < 128) ? 1 : 0;
    }
}

DEVI void conv8(const void* src, __bf16* dst, int si, int di, int isf32) {
    if (isf32) {
        const float* s = (const float*)src + si;
        bf16x8 o;
#pragma unroll
        for (int j = 0; j < 8; j++) o[j] = (__bf16)s[j];
        *(bf16x8*)(dst + di) = o;
    } else {
        *(uint4*)(dst + di) = *(const uint4*)((const __bf16*)src + si);
    }
}

// convert/copy one input array into canonical bf16 (n multiple of 8)
__global__ __launch_bounds__(256) void convert_kernel(const void* __restrict__ src,
                                                      __bf16* __restrict__ dst, int n,
                                                      const int* __restrict__ flags) {
    const int i = (blockIdx.x * 256 + threadIdx.x) * 8;
    if (i >= n) return;
    conv8(src, dst, i, i, flags[0]);
}

// three same-size arrays (1<<20 elems each) -> one contiguous dst
__global__ __launch_bounds__(256) void convert3_kernel(const void* s0, const void* s1,
                                                       const void* s2, __bf16* __restrict__ dst,
                                                       const int* __restrict__ flags) {
    const int i = (blockIdx.x * 256 + threadIdx.x) * 8;
    const int which = i >> 20;
    const int off = i & 1048575;
    const void* s = (which == 0) ? s0 : ((which == 1) ? s1 : s2);
    conv8(s, dst, off, i, flags[0]);
}

// small vectors: b1 (4096) -> d0; b2,g1,be1,g2,be2 (5 x 1024, contiguous) -> d1
struct Ptr6 { const void* p[6]; };
__global__ __launch_bounds__(256) void convert_small(Ptr6 srcs, __bf16* __restrict__ d0,
                                                     __bf16* __restrict__ d1,
                                                     const int* __restrict__ flags) {
    const int idx = (blockIdx.x * 256 + threadIdx.x) * 8;  // 9216 total
    if (idx >= 9216) return;
    const int f = flags[0];
    if (idx < 4096) {
        conv8(srcs.p[0], d0, idx, idx, f);
    } else {
        const int j = idx - 4096;
        conv8(srcs.p[1 + (j >> 10)], d1, j & 1023, j, f);
    }
}

// ---------------------------------------------------------------------------
// Fused x-convert + LN1: one block per row; reads raw x (fp32 or bf16),
// writes canonical bf16 cx AND LayerNorm'd x2.
__global__ __launch_bounds__(256) void convert_ln_kernel(
    const void* __restrict__ src, const __bf16* __restrict__ g,
    const __bf16* __restrict__ b, __bf16* __restrict__ cx,
    __bf16* __restrict__ x2, const int* __restrict__ flags) {
    const size_t row = blockIdx.x;
    const int tid = threadIdx.x;
    float v[4];
    if (flags[0]) {
        const float4 f = *((const float4*)((const float*)src + row * 1024) + tid);
        v[0] = f.x; v[1] = f.y; v[2] = f.z; v[3] = f.w;
    } else {
        const bf16x4 f = *((const bf16x4*)((const __bf16*)src + row * 1024) + tid);
#pragma unroll
        for (int i = 0; i < 4; i++) v[i] = (float)f[i];
    }
    bf16x4 o;
#pragma unroll
    for (int i = 0; i < 4; i++) o[i] = (__bf16)v[i];
    *((bf16x4*)(cx + row * 1024) + tid) = o;

    float s = v[0] + v[1] + v[2] + v[3];
    float s2 = v[0] * v[0] + v[1] * v[1] + v[2] * v[2] + v[3] * v[3];
#pragma unroll
    for (int m = 32; m >= 1; m >>= 1) {
        s += __shfl_xor(s, m, 64);
        s2 += __shfl_xor(s2, m, 64);
    }
    __shared__ float rs[4], rs2[4];
    const int wave = tid >> 6, lane = tid & 63;
    if (lane == 0) { rs[wave] = s; rs2[wave] = s2; }
    __syncthreads();
    s = rs[0] + rs[1] + rs[2] + rs[3];
    s2 = rs2[0] + rs2[1] + rs2[2] + rs2[3];
    const float mu = s * (1.0f / 1024.0f);
    const float var = s2 * (1.0f / 1024.0f) - mu * mu;
    const float inv = rsqrtf(var + 1e-5f);
#pragma unroll
    for (int i = 0; i < 4; i++) {
        const int c = tid * 4 + i;
        x2[row * 1024 + c] = (__bf16)((v[i] - mu) * inv * (float)g[c] + (float)b[c]);
    }
}

// ---------------------------------------------------------------------------
// LayerNorm: one block per row of 1024, fp32 math, bf16 out
template <typename T>
__global__ __launch_bounds__(256) void ln_kernel(const T* __restrict__ x,
                                                 const __bf16* __restrict__ g,
                                                 const __bf16* __restrict__ b,
                                                 __bf16* __restrict__ out) {
    const size_t row = blockIdx.x;
    const T* xr = x + row * 1024;
    const int tid = threadIdx.x;
    float v[4];
#pragma unroll
    for (int i = 0; i < 4; i++) v[i] = (float)xr[tid * 4 + i];
    float s = v[0] + v[1] + v[2] + v[3];
    float s2 = v[0] * v[0] + v[1] * v[1] + v[2] * v[2] + v[3] * v[3];
#pragma unroll
    for (int m = 32; m >= 1; m >>= 1) {
        s += __shfl_xor(s, m, 64);
        s2 += __shfl_xor(s2, m, 64);
    }
    __shared__ float rs[4], rs2[4];
    const int wave = tid >> 6, lane = tid & 63;
    if (lane == 0) { rs[wave] = s; rs2[wave] = s2; }
    __syncthreads();
    s = rs[0] + rs[1] + rs[2] + rs[3];
    s2 = rs2[0] + rs2[1] + rs2[2] + rs2[3];
    const float mu = s * (1.0f / 1024.0f);
    const float var = s2 * (1.0f / 1024.0f) - mu * mu;
    const float inv = rsqrtf(var + 1e-5f);
#pragma unroll
    for (int i = 0; i < 4; i++) {
        const int c = tid * 4 + i;
        out[row * 1024 + c] = (__bf16)((v[i] - mu) * inv * (float)g[c] + (float)b[c]);
    }
}

// ---------------------------------------------------------------------------
// MFMA GEMM: C[M,N] = A[M,K] @ B[N,K]^T, bf16 in, fp32 acc, OutT out.
// 128x128 tile, BK=32, 256 threads, 2-phase dbuf, XOR + XCD swizzles.
enum { EP_NONE = 0, EP_ELU1 = 1, EP_BIAS_GELU = 2, EP_BIAS_RES = 3, EP_QKV = 4 };

template <int EP, typename OutT>
__global__ __launch_bounds__(256, 4) void gemm_bt(
    const __bf16* __restrict__ A, const __bf16* __restrict__ B,
    const __bf16* __restrict__ bias, const float* resid,
    OutT* C, int M, int N, int K) {
    const int nwg = gridDim.x * gridDim.y;
    int bid = blockIdx.y * gridDim.x + blockIdx.x;
    bid = (bid & 7) * (nwg >> 3) + (bid >> 3);
    const int bm = bid / gridDim.x, bn = bid % gridDim.x;

    const int tid = threadIdx.x;
    const int wave = tid >> 6, lane = tid & 63;
    const int wm = wave & 1, wn = wave >> 1;
    const int lm = lane & 15, lq = lane >> 4;

    __shared__ __align__(16) __bf16 Asmem[2][128 * 32];
    __shared__ __align__(16) __bf16 Bsmem[2][128 * 32];

    f32x4 acc[4][4] = {};

    const __bf16* Abase = A + (size_t)bm * 128 * K;
    const __bf16* Bbase = B + (size_t)bn * 128 * K;

    const int sr = tid >> 2;
    const int sc = (((tid & 3) ^ ((tid >> 3) & 3))) << 3;
    const int wb = wave * 512;

    const __bf16* Ap0 = Abase + (size_t)sr * K + sc;
    const __bf16* Ap1 = Abase + (size_t)(sr + 64) * K + sc;
    const __bf16* Bp0 = Bbase + (size_t)sr * K + sc;
    const __bf16* Bp1 = Bbase + (size_t)(sr + 64) * K + sc;

    const int rg = ((lq ^ ((lm >> 1) & 3))) << 3;

#define STAGE(b, kk)                              \
    do {                                          \
        gload_lds16(Ap0 + (kk), &Asmem[b][wb]);   \
        gload_lds16(Ap1 + (kk), &Asmem[b][2048 + wb]); \
        gload_lds16(Bp0 + (kk), &Bsmem[b][wb]);   \
        gload_lds16(Bp1 + (kk), &Bsmem[b][2048 + wb]); \
    } while (0)

    STAGE(0, 0);
    __syncthreads();
    int cur = 0;
    for (int k0 = 0; k0 < K; k0 += 32) {
        if (k0 + 32 < K) STAGE(cur ^ 1, k0 + 32);
        bf16x8 af[4], bfv[4];
#pragma unroll
        for (int i = 0; i < 4; i++) {
            af[i]  = *(const bf16x8*)&Asmem[cur][(wm * 64 + i * 16 + lm) * 32 + rg];
            bfv[i] = *(const bf16x8*)&Bsmem[cur][(wn * 64 + i * 16 + lm) * 32 + rg];
        }
#pragma unroll
        for (int i = 0; i < 4; i++)
#pragma unroll
            for (int j = 0; j < 4; j++)
                acc[i][j] = __builtin_amdgcn_mfma_f32_16x16x32_bf16(af[i], bfv[j], acc[i][j], 0, 0, 0);
        __syncthreads();
        cur ^= 1;
    }
#undef STAGE

    const int row0 = bm * 128 + wm * 64;
    const int col0 = bn * 128 + wn * 64;
#pragma unroll
    for (int i = 0; i < 4; i++) {
#pragma unroll
        for (int j = 0; j < 4; j++) {
            const int col = col0 + j * 16 + lm;
#pragma unroll
            for (int r = 0; r < 4; r++) {
                const int row = row0 + i * 16 + lq * 4 + r;
                float v = acc[i][j][r];
                if (EP == EP_QKV) {
                    const int which = col >> 10;
                    if (which < 2) v = (v > 0.0f) ? (v + 1.0f) : __expf(v);
                    ((__bf16*)C)[(size_t)which * 8388608 + (size_t)row * 1024 + (col & 1023)] = (__bf16)v;
                    continue;
                }
                if (EP == EP_ELU1) {
                    v = (v > 0.0f) ? (v + 1.0f) : __expf(v);
                } else if (EP == EP_BIAS_GELU) {
                    v += (float)bias[col];
                    v = gelu_exact(v);
                } else if (EP == EP_BIAS_RES) {
                    v += (float)bias[col];
                    v += resid[(size_t)row * N + col];
                }
                C[(size_t)row * N + col] = (OutT)v;
            }
        }
    }
}

// ---------------------------------------------------------------------------
// 256x256-tile GEMM, 4-phase/K-tile + COUNTED vmcnt (T4, m218 mechanism).
// r11 base (1 stage-pair per phase) with stage groups regrouped by consumer
// phase: G1 = {B0,B1 | B2,B3 | A0,A2} (needed by P1/P3) issued in P1/P2/P3;
// G2 = {A1,A3} (needed by P2/P4) issued in P3. Steady-state waits are
// vmcnt(2), never 0: per-wave FIFO oldest-6 = G1(t+1), newest-2 = G2(t+1).
// vmcnt+barrier pairs make certification collective. Last tile: vmcnt(0).
__global__ __launch_bounds__(512, 1) void gemm256_gelu(
    const __bf16* __restrict__ A, const __bf16* __restrict__ B,
    const __bf16* __restrict__ bias, __bf16* __restrict__ C,
    int M, int N, int K) {
    const int nwg = gridDim.x * gridDim.y;
    int bid = blockIdx.y * gridDim.x + blockIdx.x;
    bid = (bid & 7) * (nwg >> 3) + (bid >> 3);
    const int bm = bid / gridDim.x, bn = bid % gridDim.x;

    const int tid = threadIdx.x;
    const int wave = tid >> 6, lane = tid & 63;
    const int wm = wave >> 2, wn = wave & 3;   // 2M x 4N
    const int lm = lane & 15, lq = lane >> 4;

    __shared__ __align__(16) __bf16 Asmem[2][256 * 64];
    __shared__ __align__(16) __bf16 Bsmem[2][256 * 64];

    f32x4 acc[8][4] = {};

    const int sr = tid >> 3;                              // 0..63
    const int sc = (((tid & 7) ^ ((tid >> 3) & 7))) << 3; // pre-swizzled src col
    const int wdst = wave * 512;                          // wave-uniform LDS base

    const __bf16* Ap[4];
    const __bf16* Bp[4];
#pragma unroll
    for (int p = 0; p < 4; p++) {
        Ap[p] = A + (size_t)(bm * 256 + p * 64 + sr) * K + sc;
        Bp[p] = B + (size_t)(bn * 256 + p * 64 + sr) * K + sc;
    }

    // stage pairs grouped by consumer phase (see header comment)
#define ST_B01(b, kk)                                                \
    do { gload_lds16(Bp[0] + (kk), &Bsmem[b][0 * 4096 + wdst]);      \
         gload_lds16(Bp[1] + (kk), &Bsmem[b][1 * 4096 + wdst]); } while (0)
#define ST_B23(b, kk)                                                \
    do { gload_lds16(Bp[2] + (kk), &Bsmem[b][2 * 4096 + wdst]);      \
         gload_lds16(Bp[3] + (kk), &Bsmem[b][3 * 4096 + wdst]); } while (0)
#define ST_A02(b, kk)                                                \
    do { gload_lds16(Ap[0] + (kk), &Asmem[b][0 * 4096 + wdst]);      \
         gload_lds16(Ap[2] + (kk), &Asmem[b][2 * 4096 + wdst]); } while (0)
#define ST_A13(b, kk)                                                \
    do { gload_lds16(Ap[1] + (kk), &Asmem[b][1 * 4096 + wdst]);      \
         gload_lds16(Ap[3] + (kk), &Asmem[b][3 * 4096 + wdst]); } while (0)

#define PH_DSREAD_AF(ihalf, rg)                                              \
    _Pragma("unroll")                                                        \
    for (int i = 0; i < 4; i++)                                              \
        af[i] = *(const bf16x8*)&Asmem[cur][(wm * 128 + ((ihalf) * 4 + i) * 16 + lm) * 64 + (rg)];
#define PH_DSREAD_BV(rg)                                                     \
    _Pragma("unroll")                                                        \
    for (int j = 0; j < 4; j++)                                              \
        bv[j] = *(const bf16x8*)&Bsmem[cur][(wn * 64 + j * 16 + lm) * 64 + (rg)];
#define PH_MFMA(ihalf)                                                       \
    __builtin_amdgcn_s_setprio(1);                                           \
    _Pragma("unroll")                                                        \
    for (int i = 0; i < 4; i++)                                              \
        _Pragma("unroll")                                                    \
        for (int j = 0; j < 4; j++)                                          \
            acc[(ihalf) * 4 + i][j] = __builtin_amdgcn_mfma_f32_16x16x32_bf16( \
                af[i], bv[j], acc[(ihalf) * 4 + i][j], 0, 0, 0);             \
    __builtin_amdgcn_s_setprio(0);
#define PH_BAR()                                                             \
    asm volatile("" ::: "memory");                                           \
    __builtin_amdgcn_s_barrier();                                            \
    asm volatile("" ::: "memory")

    // prologue: stage tile 0 fully, drain, certify
    ST_B01(0, 0); ST_B23(0, 0); ST_A02(0, 0); ST_A13(0, 0);
    asm volatile("s_waitcnt vmcnt(0)" ::: "memory");
    PH_BAR();

    const int gsw = lm & 7;
    const int nt = K >> 6;                                // 16 for K=1024
    int cur = 0;
    for (int t = 0; t < nt; ++t) {
        const int nb = cur ^ 1;
        const bool pf = (t + 1 < nt);
        const int nk = (t + 1) << 6;
        const int rg0 = (lq ^ gsw) << 3;                  // ks=0 granule
        const int rg1 = ((4 + lq) ^ gsw) << 3;            // ks=1 granule
        bf16x8 af[4], bv[4];
        // ---- phase 1: reads B*,A{0,2} ks0; stage B01(t+1)
        PH_DSREAD_BV(rg0);
        PH_DSREAD_AF(0, rg0);
        if (pf) ST_B01(nb, nk);
        PH_BAR();
        PH_MFMA(0);
        // certify G2(t)={A1,A3} before the barrier P2's readers pass.
        // outstanding: A13(t)[2] + B01(t+1)[2] -> vmcnt(2) waits oldest 2.
        if (pf) asm volatile("s_waitcnt vmcnt(2)" ::: "memory");
        else    asm volatile("s_waitcnt vmcnt(0)" ::: "memory");
        PH_BAR();
        // ---- phase 2: reads A{1,3} ks0 (bv reused); stage B23(t+1)
        PH_DSREAD_AF(1, rg0);
        if (pf) ST_B23(nb, nk);
        PH_BAR();
        PH_MFMA(1);
        PH_BAR();
        // ---- phase 3: reads B*,A{0,2} ks1; stage A02(t+1) + A13(t+1)
        PH_DSREAD_BV(rg1);
        PH_DSREAD_AF(0, rg1);
        if (pf) { ST_A02(nb, nk); ST_A13(nb, nk); }
        PH_BAR();
        PH_MFMA(0);
        PH_BAR();
        // ---- phase 4: reads A{1,3} ks1; certify G1(t+1) with COUNTED wait:
        // outstanding = B01,B23,A02 (6 oldest) + A13 (2 newest) -> vmcnt(2).
        PH_DSREAD_AF(1, rg1);
        PH_BAR();
        PH_MFMA(1);
        if (pf) asm volatile("s_waitcnt vmcnt(2)" ::: "memory");
        PH_BAR();
        cur ^= 1;
    }
#undef ST_B01
#undef ST_B23
#undef ST_A02
#undef ST_A13
#undef PH_DSREAD_AF
#undef PH_DSREAD_BV
#undef PH_MFMA
#undef PH_BAR

    const int row0 = bm * 256 + wm * 128;
    const int col0 = bn * 256 + wn * 64;
#pragma unroll
    for (int i = 0; i < 8; i++) {
#pragma unroll
        for (int j = 0; j < 4; j++) {
            const int col = col0 + j * 16 + lm;
            const float bcol = (float)bias[col];
#pragma unroll
            for (int r = 0; r < 4; r++) {
                const int row = row0 + i * 16 + lq * 4 + r;
                C[(size_t)row * N + col] = (__bf16)gelu_exact(acc[i][j][r] + bcol);
            }
        }
    }
}

// ---------------------------------------------------------------------------
// BK=64 GEMM for w2 (bias + resid epilogue, fp32 out). 2x MFMA-per-barrier.
__global__ __launch_bounds__(256, 2) void gemm_bt_k64(
    const __bf16* __restrict__ A, const __bf16* __restrict__ B,
    const __bf16* __restrict__ bias, const float* resid,
    float* C, int M, int N, int K) {
    const int nwg = gridDim.x * gridDim.y;
    int bid = blockIdx.y * gridDim.x + blockIdx.x;
    bid = (bid & 7) * (nwg >> 3) + (bid >> 3);
    const int bm = bid / gridDim.x, bn = bid % gridDim.x;

    const int tid = threadIdx.x;
    const int wave = tid >> 6, lane = tid & 63;
    const int wm = wave & 1, wn = wave >> 1;
    const int lm = lane & 15, lq = lane >> 4;

    __shared__ __align__(16) __bf16 Asmem[2][128 * 64];
    __shared__ __align__(16) __bf16 Bsmem[2][128 * 64];

    f32x4 acc[4][4] = {};

    const __bf16* Abase = A + (size_t)bm * 128 * K;
    const __bf16* Bbase = B + (size_t)bn * 128 * K;

    const int sr = tid >> 3;
    const int sc = (((tid & 7) ^ ((tid >> 3) & 7))) << 3;
    const int wb = wave * 512;

    const __bf16* Ap[4];
    const __bf16* Bp[4];
#pragma unroll
    for (int p = 0; p < 4; p++) {
        Ap[p] = Abase + (size_t)(p * 32 + sr) * K + sc;
        Bp[p] = Bbase + (size_t)(p * 32 + sr) * K + sc;
    }

#define STAGE64(b, kk)                                        \
    do {                                                      \
        _Pragma("unroll")                                     \
        for (int p = 0; p < 4; p++) {                         \
            gload_lds16(Ap[p] + (kk), &Asmem[b][p * 2048 + wb]); \
            gload_lds16(Bp[p] + (kk), &Bsmem[b][p * 2048 + wb]); \
        }                                                     \
    } while (0)

    STAGE64(0, 0);
    __syncthreads();
    int cur = 0;
    for (int k0 = 0; k0 < K; k0 += 64) {
        if (k0 + 64 < K) STAGE64(cur ^ 1, k0 + 64);
        bf16x8 af[2][4], bfv[2][4];
#pragma unroll
        for (int h = 0; h < 2; h++) {
            const int rg = ((h * 4 + lq) ^ (lm & 7)) << 3;
#pragma unroll
            for (int i = 0; i < 4; i++) {
                af[h][i]  = *(const bf16x8*)&Asmem[cur][(wm * 64 + i * 16 + lm) * 64 + rg];
                bfv[h][i] = *(const bf16x8*)&Bsmem[cur][(wn * 64 + i * 16 + lm) * 64 + rg];
            }
        }
#pragma unroll
        for (int h = 0; h < 2; h++)
#pragma unroll
            for (int i = 0; i < 4; i++)
#pragma unroll
                for (int j = 0; j < 4; j++)
                    acc[i][j] = __builtin_amdgcn_mfma_f32_16x16x32_bf16(af[h][i], bfv[h][j], acc[i][j], 0, 0, 0);
        __syncthreads();
        cur ^= 1;
    }
#undef STAGE64

    const int row0 = bm * 128 + wm * 64;
    const int col0 = bn * 128 + wn * 64;
#pragma unroll
    for (int i = 0; i < 4; i++) {
#pragma unroll
        for (int j = 0; j < 4; j++) {
            const int col = col0 + j * 16 + lm;
            const float bcol = (float)bias[col];
#pragma unroll
            for (int r = 0; r < 4; r++) {
                const int row = row0 + i * 16 + lq * 4 + r;
                float v = acc[i][j][r] + bcol;
                v += resid[(size_t)row * N + col];
                C[(size_t)row * N + col] = v;
            }
        }
    }
}

// ---------------------------------------------------------------------------
// KV partials: block (nh, sc, vh) computes KV over 256 s-rows, written
// TRANSPOSED ([v][d]) so attn_out's MFMA B-operand is row-major [N=v, K=d].
__global__ __launch_bounds__(256) void kv_kernel(const __bf16* __restrict__ Kf,
                                                 const __bf16* __restrict__ Vf,
                                                 float* __restrict__ pkv,
                                                 float* __restrict__ pks) {
    const int nh = blockIdx.x, sc = blockIdx.y, vh = blockIdx.z;
    const int n = nh >> 3, h = nh & 7;
    const int tid = threadIdx.x;
    const int tv = tid & 15, td = tid >> 4;
    __shared__ __align__(16) __bf16 Kt[32 * 128];
    __shared__ __align__(16) __bf16 Vt[32 * 64];
    float acc[8][4] = {};
    float ks[8] = {};
    const size_t rowbase = (size_t)n * 4096 + (size_t)sc * 256;
    for (int s0 = 0; s0 < 256; s0 += 32) {
#pragma unroll
        for (int rep = 0; rep < 2; rep++) {
            const int s = tid + rep * 256;
            const int r = s >> 4, cs = (s & 15) * 8;
            const size_t gidx = (rowbase + s0 + r) * 1024 + h * 128 + cs;
            *(bf16x8*)&Kt[r * 128 + cs] = *(const bf16x8*)&Kf[gidx];
        }
        {
            const int r = tid >> 3, cs = (tid & 7) * 8;
            const size_t gidx = (rowbase + s0 + r) * 1024 + h * 128 + vh * 64 + cs;
            *(bf16x8*)&Vt[r * 64 + cs] = *(const bf16x8*)&Vf[gidx];
        }
        __syncthreads();
#pragma unroll 4
        for (int s = 0; s < 32; s++) {
            const bf16x8 k8 = *(const bf16x8*)&Kt[s * 128 + td * 8];
            const bf16x4 v4 = *(const bf16x4*)&Vt[s * 64 + tv * 4];
            float kk[8], vv[4];
#pragma unroll
            for (int i = 0; i < 8; i++) kk[i] = (float)k8[i];
#pragma unroll
            for (int j = 0; j < 4; j++) vv[j] = (float)v4[j];
#pragma unroll
            for (int i = 0; i < 8; i++) {
                ks[i] += kk[i];
#pragma unroll
                for (int j = 0; j < 4; j++) acc[i][j] += kk[i] * vv[j];
            }
        }
        __syncthreads();
    }
    float* dst = pkv + ((size_t)sc * 16 + nh) * 16384;
#pragma unroll
    for (int j = 0; j < 4; j++)
#pragma unroll
        for (int i = 0; i < 8; i++)
            dst[(vh * 64 + tv * 4 + j) * 128 + td * 8 + i] = acc[i][j];
    if (vh == 0 && tv == 0) {
        float* ds2 = pks + ((size_t)sc * 16 + nh) * 128;
#pragma unroll
        for (int i = 0; i < 8; i++) ds2[td * 8 + i] = ks[i];
    }
}

// reduce 16 chunks -> kvbT (bf16, [nh][v][d]) + ksf
__global__ __launch_bounds__(256) void kv_reduce(const float* __restrict__ pkv,
                                                 const float* __restrict__ pks,
                                                 __bf16* __restrict__ kvbT,
                                                 float* __restrict__ ksf) {
    const int idx = blockIdx.x * 256 + threadIdx.x;
    float s = 0.0f;
#pragma unroll
    for (int c = 0; c < 16; c++) s += pkv[(size_t)c * 262144 + idx];
    kvbT[idx] = (__bf16)s;
    if (idx < 2048) {
        float t = 0.0f;
#pragma unroll
        for (int c = 0; c < 16; c++) t += pks[c * 2048 + idx];
        ksf[idx] = t;
    }
}

__global__ __launch_bounds__(256) void z_kernel(const __bf16* __restrict__ Qf,
                                                const float* __restrict__ ksf,
                                                float* __restrict__ zbuf) {
    const int idx = blockIdx.x * 256 + threadIdx.x;
    const int h = idx & 7;
    const size_t row = (size_t)(idx >> 3);
    const __bf16* q = Qf + row * 1024 + h * 128;
    const float* ks = ksf + ((size_t)((row >> 12) * 8 + h)) * 128;
    float s = 0.0f;
    for (int d = 0; d < 128; d += 8) {
        const bf16x8 q8 = *(const bf16x8*)&q[d];
#pragma unroll
        for (int j = 0; j < 8; j++) s += (float)q8[j] * ks[d + j];
    }
    zbuf[idx] = 1.0f / (s + 1e-6f);
}

// attn out + residual via MFMA: xmid = x + (Q @ KV) * z per head.
__global__ __launch_bounds__(256, 3) void attn_out_kernel(
    const __bf16* __restrict__ x, const __bf16* __restrict__ Qf,
    const __bf16* __restrict__ kvbT, const float* __restrict__ zbuf,
    float* __restrict__ xmid) {
    const int nh = blockIdx.x, lc = blockIdx.y;
    const int n = nh >> 3, h = nh & 7;
    const int tid = threadIdx.x;
    const int wv = tid >> 6, lane = tid & 63;
    const int lm = lane & 15, lq = lane >> 4;
    __shared__ __align__(16) __bf16 KVs[128 * 128];
    __shared__ __align__(16) __bf16 Qs[64 * 128];
    __shared__ float Zs[64];
    const __bf16* kv = kvbT + (size_t)nh * 16384;
#pragma unroll
    for (int rep = 0; rep < 8; rep++) {
        const int i = tid + rep * 256;
        const int r = i >> 4, c8 = (i & 15) * 8;
        *(bf16x8*)&KVs[swz128(r, c8)] = *(const bf16x8*)&kv[i * 8];
    }
    const size_t gr0 = (size_t)n * 4096 + (size_t)lc * 64;
#pragma unroll
    for (int rep = 0; rep < 4; rep++) {
        const int s = tid + rep * 256;
        const int r = s >> 4, cs = (s & 15) * 8;
        *(bf16x8*)&Qs[swz128(r, cs)] =
            *(const bf16x8*)&Qf[(gr0 + r) * 1024 + h * 128 + cs];
    }
    if (tid < 64) Zs[tid] = zbuf[(gr0 + tid) * 8 + h];
    __syncthreads();

    const int xmask = (lm & 7) << 3;
    f32x4 acc[4][2] = {};
#pragma unroll
    for (int k0 = 0; k0 < 128; k0 += 32) {
        const int kk = (k0 + lq * 8) ^ xmask;
        bf16x8 af[4], bv[2];
#pragma unroll
        for (int i = 0; i < 4; i++)
            af[i] = *(const bf16x8*)&Qs[(i * 16 + lm) * 128 + kk];
#pragma unroll
        for (int j = 0; j < 2; j++)
            bv[j] = *(const bf16x8*)&KVs[(wv * 32 + j * 16 + lm) * 128 + kk];
#pragma unroll
        for (int i = 0; i < 4; i++)
#pragma unroll
            for (int j = 0; j < 2; j++)
                acc[i][j] = __builtin_amdgcn_mfma_f32_16x16x32_bf16(af[i], bv[j], acc[i][j], 0, 0, 0);
    }
#pragma unroll
    for (int i = 0; i < 4; i++) {
#pragma unroll
        for (int j = 0; j < 2; j++) {
            const int col = wv * 32 + j * 16 + lm;
#pragma unroll
            for (int r = 0; r < 4; r++) {
                const int lr = i * 16 + lq * 4 + r;
                const size_t gi = (gr0 + lr) * 1024 + h * 128 + col;
                xmid[gi] = (float)x[gi] + acc[i][j][r] * Zs[lr];
            }
        }
    }
}

// ---------------------------------------------------------------------------
extern "C" void kernel_launch(void* const* d_in, const int* in_sizes, int n_in,
                              void* d_out, int out_size, void* d_ws, size_t ws_size,
                              hipStream_t stream) {
    float* out = (float*)d_out;   // output is FP32 (reference output dtype)
    char* ws = (char*)d_ws;

    const int nx = 8388608, nw = 1048576, nw1 = 4194304, nb1 = 4096, ng = 1024;
    size_t off = 0;
    __bf16* cx   = (__bf16*)(ws + off); off += (size_t)nx * 2;
    __bf16* cwq  = (__bf16*)(ws + off); off += (size_t)nw * 2;   // cwq/cwk/cwv
    __bf16* cwk  = (__bf16*)(ws + off); off += (size_t)nw * 2;   // contiguous:
    __bf16* cwv  = (__bf16*)(ws + off); off += (size_t)nw * 2;   // [3072,1024]
    __bf16* cw1  = (__bf16*)(ws + off); off += (size_t)nw1 * 2;
    __bf16* cb1  = (__bf16*)(ws + off); off += (size_t)nb1 * 2;
    __bf16* cw2  = (__bf16*)(ws + off); off += (size_t)nw1 * 2;
    __bf16* cb2  = (__bf16*)(ws + off); off += (size_t)ng * 2;   // cb2..cbe2
    __bf16* cg1  = (__bf16*)(ws + off); off += (size_t)ng * 2;   // contiguous
    __bf16* cbe1 = (__bf16*)(ws + off); off += (size_t)ng * 2;   // 5x1024
    __bf16* cg2  = (__bf16*)(ws + off); off += (size_t)ng * 2;
    __bf16* cbe2 = (__bf16*)(ws + off); off += (size_t)ng * 2;
    int* flags = (int*)(ws + off); off += 64;
    (void)cwk; (void)cwv; (void)cg1; (void)cbe1; (void)cg2; (void)cbe2;

    char* PB = ws + off;
    __bf16* x2   = (__bf16*)(PB);                 // LN1 out; later LN2 out (16MB)
    __bf16* Qf   = (__bf16*)(PB + 16777216);      // Q (16MB), QKV contiguous
    __bf16* Kf   = (__bf16*)(PB + 33554432);      // K (16MB)
    __bf16* Vf   = (__bf16*)(PB + 50331648);      // V (16MB)
    float*  pkv  = (float*)(PB + 67108864);       // 16MB, ends 83886080
    float*  pks  = (float*)(PB + 83886080);
    float*  ksf  = (float*)(PB + 84017152);
    float*  zbuf = (float*)(PB + 84025344);
    __bf16* kvbT = (__bf16*)(PB + 84287488);      // ends PB+84,811,776
    __bf16* hbuf = (__bf16*)(PB + 16777216);      // MLP h [8192,4096] bf16 64MB,
                                                  // overlays dead Qf/Kf/Vf/pkv
    float*  xmid = out;                           // attn residual lives in d_out

    // 0. sniff dtype + canonicalize inputs to bf16
    sniff_kernel<<<1, 256, 0, stream>>>((const unsigned short*)d_in[0], flags);
    convert3_kernel<<<3 * nw / 2048, 256, 0, stream>>>(d_in[1], d_in[2], d_in[3], cwq, flags);
    convert_kernel<<<nw1 / 2048, 256, 0, stream>>>(d_in[4], cw1, nw1, flags);
    convert_kernel<<<nw1 / 2048, 256, 0, stream>>>(d_in[6], cw2, nw1, flags);
    Ptr6 sp;
    sp.p[0] = d_in[5];  sp.p[1] = d_in[7];  sp.p[2] = d_in[8];
    sp.p[3] = d_in[9];  sp.p[4] = d_in[10]; sp.p[5] = d_in[11];
    convert_small<<<5, 256, 0, stream>>>(sp, cb1, cb2, flags);

    // 1. fused x-convert + LN1 (writes cx and x2 in one pass over x)
    convert_ln_kernel<<<8192, 256, 0, stream>>>(d_in[0], cg1, cbe1, cx, x2, flags);
    // 2. fused QKV projection: x2[8192,1024] @ [wq;wk;wv]^T -> Q|K|V
    gemm_bt<EP_QKV, __bf16><<<dim3(3072 / 128, 8192 / 128), 256, 0, stream>>>(
        x2, cwq, nullptr, nullptr, Qf, 8192, 3072, 1024);
    // 3. KV + Ksum (v-split: 512 blocks), transposed partials -> kvbT
    kv_kernel<<<dim3(16, 16, 2), 256, 0, stream>>>(Kf, Vf, pkv, pks);
    kv_reduce<<<1024, 256, 0, stream>>>(pkv, pks, kvbT, ksf);
    // 4. Z, attention out (MFMA) + residual -> xmid (= d_out, fp32)
    z_kernel<<<256, 256, 0, stream>>>(Qf, ksf, zbuf);
    attn_out_kernel<<<dim3(16, 64), 256, 0, stream>>>(cx, Qf, kvbT, zbuf, xmid);
    // 5. LN2 + MLP. w1 via 256^2 counted-vmcnt 4-phase; w2 via BK=64 kernel.
    ln_kernel<float><<<8192, 256, 0, stream>>>(xmid, cg2, cbe2, x2);
    gemm256_gelu<<<dim3(4096 / 256, 8192 / 256), 512, 0, stream>>>(
        x2, cw1, cb1, hbuf, 8192, 4096, 1024);
    gemm_bt_k64<<<dim3(1024 / 128, 8192 / 128), 256, 0, stream>>>(
        hbuf, cw2, cb2, xmid, out, 8192, 1024, 4096);
}

// Round 15
// 450.908 us; speedup vs baseline: 1.0211x; 1.0211x over previous
//
#include <hip/hip_runtime.h>
#include <hip/hip_bf16.h>
#include <math.h>

typedef __bf16 bf16x8 __attribute__((ext_vector_type(8)));
typedef __bf16 bf16x4 __attribute__((ext_vector_type(4)));
typedef float f32x4 __attribute__((ext_vector_type(4)));

#define DEVI __device__ __forceinline__

// async global->LDS DMA, 16B per lane. LDS dest is wave-uniform base + lane*16.
DEVI void gload_lds16(const __bf16* g, __bf16* l) {
    __builtin_amdgcn_global_load_lds(
        (const __attribute__((address_space(1))) unsigned int*)g,
        (__attribute__((address_space(3))) unsigned int*)l, 16, 0, 0);
}

// Abramowitz-Stegun 7.1.26 erf: |err| <= 1.5e-7, branch-free.
DEVI float fast_erf(float x) {
    const float ax = __builtin_fabsf(x);
    const float t = __builtin_amdgcn_rcpf(__builtin_fmaf(0.3275911f, ax, 1.0f));
    float p = __builtin_fmaf(1.061405429f, t, -1.453152027f);
    p = __builtin_fmaf(p, t, 1.421413741f);
    p = __builtin_fmaf(p, t, -0.284496736f);
    p = __builtin_fmaf(p, t, 0.254829592f);
    const float e = __expf(-ax * ax);
    const float r = __builtin_fmaf(-p * t, e, 1.0f);
    return __builtin_copysignf(r, x);
}

DEVI float gelu_exact(float v) {
    return 0.5f * v * (1.0f + fast_erf(v * 0.70710678118654752f));
}

// XOR swizzle for [rows][128] bf16 LDS tiles read column-slice-wise.
DEVI int swz128(int row, int col) { return row * 128 + (col ^ ((row & 7) << 3)); }

// ---------------------------------------------------------------------------
// dtype sniffer (tri-modal). flag[0]=1 -> inputs are fp32 storage.
__global__ void sniff_kernel(const unsigned short* __restrict__ x, int* flags) {
    const int tid = threadIdx.x;  // 256
    const unsigned short u = x[tid * 2];
    const int e = (u >> 7) & 0xFF;
    const int zero = (u == 0) ? 1 : 0;
    const int sane = ((e >= 0x71 && e <= 0x8E) || ((u & 0x7FFF) == 0)) ? 1 : 0;
    const unsigned long long mz = __ballot(zero != 0);
    const unsigned long long ms = __ballot(sane != 0);
    __shared__ int wz[4], wsn[4];
    if ((tid & 63) == 0) { wz[tid >> 6] = __popcll(mz); wsn[tid >> 6] = __popcll(ms); }
    __syncthreads();
    if (tid == 0) {
        const int nz = wz[0] + wz[1] + wz[2] + wz[3];
        const int ns = wsn[0] + wsn[1] + wsn[2] + wsn[3];
        flags[0] = (nz >= 192 || ns < 128) ? 1 : 0;
    }
}

DEVI void conv8(const void* src, __bf16* dst, int si, int di, int isf32) {
    if (isf32) {
        const float* s = (const float*)src + si;
        bf16x8 o;
#pragma unroll
        for (int j = 0; j < 8; j++) o[j] = (__bf16)s[j];
        *(bf16x8*)(dst + di) = o;
    } else {
        *(uint4*)(dst + di) = *(const uint4*)((const __bf16*)src + si);
    }
}

// convert/copy one input array into canonical bf16 (n multiple of 8)
__global__ __launch_bounds__(256) void convert_kernel(const void* __restrict__ src,
                                                      __bf16* __restrict__ dst, int n,
                                                      const int* __restrict__ flags) {
    const int i = (blockIdx.x * 256 + threadIdx.x) * 8;
    if (i >= n) return;
    conv8(src, dst, i, i, flags[0]);
}

// three same-size arrays (1<<20 elems each) -> one contiguous dst
__global__ __launch_bounds__(256) void convert3_kernel(const void* s0, const void* s1,
                                                       const void* s2, __bf16* __restrict__ dst,
                                                       const int* __restrict__ flags) {
    const int i = (blockIdx.x * 256 + threadIdx.x) * 8;
    const int which = i >> 20;
    const int off = i & 1048575;
    const void* s = (which == 0) ? s0 : ((which == 1) ? s1 : s2);
    conv8(s, dst, off, i, flags[0]);
}

// small vectors: b1 (4096) -> d0; b2,g1,be1,g2,be2 (5 x 1024, contiguous) -> d1
struct Ptr6 { const void* p[6]; };
__global__ __launch_bounds__(256) void convert_small(Ptr6 srcs, __bf16* __restrict__ d0,
                                                     __bf16* __restrict__ d1,
                                                     const int* __restrict__ flags) {
    const int idx = (blockIdx.x * 256 + threadIdx.x) * 8;  // 9216 total
    if (idx >= 9216) return;
    const int f = flags[0];
    if (idx < 4096) {
        conv8(srcs.p[0], d0, idx, idx, f);
    } else {
        const int j = idx - 4096;
        conv8(srcs.p[1 + (j >> 10)], d1, j & 1023, j, f);
    }
}

// ---------------------------------------------------------------------------
// Fused x-convert + LN1: one block per row; reads raw x (fp32 or bf16),
// writes canonical bf16 cx AND LayerNorm'd x2.
__global__ __launch_bounds__(256) void convert_ln_kernel(
    const void* __restrict__ src, const __bf16* __restrict__ g,
    const __bf16* __restrict__ b, __bf16* __restrict__ cx,
    __bf16* __restrict__ x2, const int* __restrict__ flags) {
    const size_t row = blockIdx.x;
    const int tid = threadIdx.x;
    float v[4];
    if (flags[0]) {
        const float4 f = *((const float4*)((const float*)src + row * 1024) + tid);
        v[0] = f.x; v[1] = f.y; v[2] = f.z; v[3] = f.w;
    } else {
        const bf16x4 f = *((const bf16x4*)((const __bf16*)src + row * 1024) + tid);
#pragma unroll
        for (int i = 0; i < 4; i++) v[i] = (float)f[i];
    }
    bf16x4 o;
#pragma unroll
    for (int i = 0; i < 4; i++) o[i] = (__bf16)v[i];
    *((bf16x4*)(cx + row * 1024) + tid) = o;

    float s = v[0] + v[1] + v[2] + v[3];
    float s2 = v[0] * v[0] + v[1] * v[1] + v[2] * v[2] + v[3] * v[3];
#pragma unroll
    for (int m = 32; m >= 1; m >>= 1) {
        s += __shfl_xor(s, m, 64);
        s2 += __shfl_xor(s2, m, 64);
    }
    __shared__ float rs[4], rs2[4];
    const int wave = tid >> 6, lane = tid & 63;
    if (lane == 0) { rs[wave] = s; rs2[wave] = s2; }
    __syncthreads();
    s = rs[0] + rs[1] + rs[2] + rs[3];
    s2 = rs2[0] + rs2[1] + rs2[2] + rs2[3];
    const float mu = s * (1.0f / 1024.0f);
    const float var = s2 * (1.0f / 1024.0f) - mu * mu;
    const float inv = rsqrtf(var + 1e-5f);
#pragma unroll
    for (int i = 0; i < 4; i++) {
        const int c = tid * 4 + i;
        x2[row * 1024 + c] = (__bf16)((v[i] - mu) * inv * (float)g[c] + (float)b[c]);
    }
}

// ---------------------------------------------------------------------------
// LayerNorm: one block per row of 1024, fp32 math, bf16 out
template <typename T>
__global__ __launch_bounds__(256) void ln_kernel(const T* __restrict__ x,
                                                 const __bf16* __restrict__ g,
                                                 const __bf16* __restrict__ b,
                                                 __bf16* __restrict__ out) {
    const size_t row = blockIdx.x;
    const T* xr = x + row * 1024;
    const int tid = threadIdx.x;
    float v[4];
#pragma unroll
    for (int i = 0; i < 4; i++) v[i] = (float)xr[tid * 4 + i];
    float s = v[0] + v[1] + v[2] + v[3];
    float s2 = v[0] * v[0] + v[1] * v[1] + v[2] * v[2] + v[3] * v[3];
#pragma unroll
    for (int m = 32; m >= 1; m >>= 1) {
        s += __shfl_xor(s, m, 64);
        s2 += __shfl_xor(s2, m, 64);
    }
    __shared__ float rs[4], rs2[4];
    const int wave = tid >> 6, lane = tid & 63;
    if (lane == 0) { rs[wave] = s; rs2[wave] = s2; }
    __syncthreads();
    s = rs[0] + rs[1] + rs[2] + rs[3];
    s2 = rs2[0] + rs2[1] + rs2[2] + rs2[3];
    const float mu = s * (1.0f / 1024.0f);
    const float var = s2 * (1.0f / 1024.0f) - mu * mu;
    const float inv = rsqrtf(var + 1e-5f);
#pragma unroll
    for (int i = 0; i < 4; i++) {
        const int c = tid * 4 + i;
        out[row * 1024 + c] = (__bf16)((v[i] - mu) * inv * (float)g[c] + (float)b[c]);
    }
}

// ---------------------------------------------------------------------------
// MFMA GEMM: C[M,N] = A[M,K] @ B[N,K]^T, bf16 in, fp32 acc, OutT out.
// 128x128 tile, BK=32, 256 threads, 2-phase dbuf, XOR + XCD swizzles.
enum { EP_NONE = 0, EP_ELU1 = 1, EP_BIAS_GELU = 2, EP_BIAS_RES = 3, EP_QKV = 4 };

template <int EP, typename OutT>
__global__ __launch_bounds__(256, 4) void gemm_bt(
    const __bf16* __restrict__ A, const __bf16* __restrict__ B,
    const __bf16* __restrict__ bias, const float* resid,
    OutT* C, int M, int N, int K) {
    const int nwg = gridDim.x * gridDim.y;
    int bid = blockIdx.y * gridDim.x + blockIdx.x;
    bid = (bid & 7) * (nwg >> 3) + (bid >> 3);
    const int bm = bid / gridDim.x, bn = bid % gridDim.x;

    const int tid = threadIdx.x;
    const int wave = tid >> 6, lane = tid & 63;
    const int wm = wave & 1, wn = wave >> 1;
    const int lm = lane & 15, lq = lane >> 4;

    __shared__ __align__(16) __bf16 Asmem[2][128 * 32];
    __shared__ __align__(16) __bf16 Bsmem[2][128 * 32];

    f32x4 acc[4][4] = {};

    const __bf16* Abase = A + (size_t)bm * 128 * K;
    const __bf16* Bbase = B + (size_t)bn * 128 * K;

    const int sr = tid >> 2;
    const int sc = (((tid & 3) ^ ((tid >> 3) & 3))) << 3;
    const int wb = wave * 512;

    const __bf16* Ap0 = Abase + (size_t)sr * K + sc;
    const __bf16* Ap1 = Abase + (size_t)(sr + 64) * K + sc;
    const __bf16* Bp0 = Bbase + (size_t)sr * K + sc;
    const __bf16* Bp1 = Bbase + (size_t)(sr + 64) * K + sc;

    const int rg = ((lq ^ ((lm >> 1) & 3))) << 3;

#define STAGE(b, kk)                              \
    do {                                          \
        gload_lds16(Ap0 + (kk), &Asmem[b][wb]);   \
        gload_lds16(Ap1 + (kk), &Asmem[b][2048 + wb]); \
        gload_lds16(Bp0 + (kk), &Bsmem[b][wb]);   \
        gload_lds16(Bp1 + (kk), &Bsmem[b][2048 + wb]); \
    } while (0)

    STAGE(0, 0);
    __syncthreads();
    int cur = 0;
    for (int k0 = 0; k0 < K; k0 += 32) {
        if (k0 + 32 < K) STAGE(cur ^ 1, k0 + 32);
        bf16x8 af[4], bfv[4];
#pragma unroll
        for (int i = 0; i < 4; i++) {
            af[i]  = *(const bf16x8*)&Asmem[cur][(wm * 64 + i * 16 + lm) * 32 + rg];
            bfv[i] = *(const bf16x8*)&Bsmem[cur][(wn * 64 + i * 16 + lm) * 32 + rg];
        }
#pragma unroll
        for (int i = 0; i < 4; i++)
#pragma unroll
            for (int j = 0; j < 4; j++)
                acc[i][j] = __builtin_amdgcn_mfma_f32_16x16x32_bf16(af[i], bfv[j], acc[i][j], 0, 0, 0);
        __syncthreads();
        cur ^= 1;
    }
#undef STAGE

    const int row0 = bm * 128 + wm * 64;
    const int col0 = bn * 128 + wn * 64;
#pragma unroll
    for (int i = 0; i < 4; i++) {
#pragma unroll
        for (int j = 0; j < 4; j++) {
            const int col = col0 + j * 16 + lm;
#pragma unroll
            for (int r = 0; r < 4; r++) {
                const int row = row0 + i * 16 + lq * 4 + r;
                float v = acc[i][j][r];
                if (EP == EP_QKV) {
                    const int which = col >> 10;
                    if (which < 2) v = (v > 0.0f) ? (v + 1.0f) : __expf(v);
                    ((__bf16*)C)[(size_t)which * 8388608 + (size_t)row * 1024 + (col & 1023)] = (__bf16)v;
                    continue;
                }
                if (EP == EP_ELU1) {
                    v = (v > 0.0f) ? (v + 1.0f) : __expf(v);
                } else if (EP == EP_BIAS_GELU) {
                    v += (float)bias[col];
                    v = gelu_exact(v);
                } else if (EP == EP_BIAS_RES) {
                    v += (float)bias[col];
                    v += resid[(size_t)row * N + col];
                }
                C[(size_t)row * N + col] = (OutT)v;
            }
        }
    }
}

// ---------------------------------------------------------------------------
// 256x256-tile GEMM, 4-phase/K-tile schedule for w1 (r11 verified optimum:
// ONE stage-issue pair per phase, single vmcnt(0) drain per tile after
// phase 4's MFMA cover. Measured ledger: coarse-split (r10) null,
// front-load (r12) -28%, counted-vmcnt regroup (r14) -4% — this placement
// is the stable maximum of the structure).
__global__ __launch_bounds__(512, 1) void gemm256_gelu(
    const __bf16* __restrict__ A, const __bf16* __restrict__ B,
    const __bf16* __restrict__ bias, __bf16* __restrict__ C,
    int M, int N, int K) {
    const int nwg = gridDim.x * gridDim.y;
    int bid = blockIdx.y * gridDim.x + blockIdx.x;
    bid = (bid & 7) * (nwg >> 3) + (bid >> 3);
    const int bm = bid / gridDim.x, bn = bid % gridDim.x;

    const int tid = threadIdx.x;
    const int wave = tid >> 6, lane = tid & 63;
    const int wm = wave >> 2, wn = wave & 3;   // 2M x 4N
    const int lm = lane & 15, lq = lane >> 4;

    __shared__ __align__(16) __bf16 Asmem[2][256 * 64];
    __shared__ __align__(16) __bf16 Bsmem[2][256 * 64];

    f32x4 acc[8][4] = {};

    const int sr = tid >> 3;                              // 0..63
    const int sc = (((tid & 7) ^ ((tid >> 3) & 7))) << 3; // pre-swizzled src col
    const int wdst = wave * 512;                          // wave-uniform LDS base

    const __bf16* Ap[4];
    const __bf16* Bp[4];
#pragma unroll
    for (int p = 0; p < 4; p++) {
        Ap[p] = A + (size_t)(bm * 256 + p * 64 + sr) * K + sc;
        Bp[p] = B + (size_t)(bn * 256 + p * 64 + sr) * K + sc;
    }

    // which: 0 = A chunks 0,1; 1 = A chunks 2,3; 2 = B chunks 0,1; 3 = B 2,3
#define STAGE2(b, kk, w)                                                     \
    do {                                                                     \
        if ((w) == 0) {                                                      \
            gload_lds16(Ap[0] + (kk), &Asmem[b][0 * 4096 + wdst]);           \
            gload_lds16(Ap[1] + (kk), &Asmem[b][1 * 4096 + wdst]);           \
        } else if ((w) == 1) {                                               \
            gload_lds16(Ap[2] + (kk), &Asmem[b][2 * 4096 + wdst]);           \
            gload_lds16(Ap[3] + (kk), &Asmem[b][3 * 4096 + wdst]);           \
        } else if ((w) == 2) {                                               \
            gload_lds16(Bp[0] + (kk), &Bsmem[b][0 * 4096 + wdst]);           \
            gload_lds16(Bp[1] + (kk), &Bsmem[b][1 * 4096 + wdst]);           \
        } else {                                                             \
            gload_lds16(Bp[2] + (kk), &Bsmem[b][2 * 4096 + wdst]);           \
            gload_lds16(Bp[3] + (kk), &Bsmem[b][3 * 4096 + wdst]);           \
        }                                                                    \
    } while (0)

#define PH_DSREAD_AF(ihalf, rg)                                              \
    _Pragma("unroll")                                                        \
    for (int i = 0; i < 4; i++)                                              \
        af[i] = *(const bf16x8*)&Asmem[cur][(wm * 128 + ((ihalf) * 4 + i) * 16 + lm) * 64 + (rg)];
#define PH_DSREAD_BV(rg)                                                     \
    _Pragma("unroll")                                                        \
    for (int j = 0; j < 4; j++)                                              \
        bv[j] = *(const bf16x8*)&Bsmem[cur][(wn * 64 + j * 16 + lm) * 64 + (rg)];
#define PH_MFMA(ihalf)                                                       \
    __builtin_amdgcn_s_setprio(1);                                           \
    _Pragma("unroll")                                                        \
    for (int i = 0; i < 4; i++)                                              \
        _Pragma("unroll")                                                    \
        for (int j = 0; j < 4; j++)                                          \
            acc[(ihalf) * 4 + i][j] = __builtin_amdgcn_mfma_f32_16x16x32_bf16( \
                af[i], bv[j], acc[(ihalf) * 4 + i][j], 0, 0, 0);             \
    __builtin_amdgcn_s_setprio(0);
#define PH_BAR()                                                             \
    asm volatile("" ::: "memory");                                           \
    __builtin_amdgcn_s_barrier();                                            \
    asm volatile("" ::: "memory")

    // prologue: stage tile 0 fully, certify
    STAGE2(0, 0, 0);
    STAGE2(0, 0, 1);
    STAGE2(0, 0, 2);
    STAGE2(0, 0, 3);
    asm volatile("s_waitcnt vmcnt(0)" ::: "memory");
    PH_BAR();

    const int gsw = lm & 7;
    const int nt = K >> 6;                                // 16 for K=1024
    int cur = 0;
    for (int t = 0; t < nt; ++t) {
        const int nb = cur ^ 1;
        const bool pf = (t + 1 < nt);
        const int nk = (t + 1) << 6;
        const int rg0 = (lq ^ gsw) << 3;                  // ks=0 granule
        const int rg1 = ((4 + lq) ^ gsw) << 3;            // ks=1 granule
        bf16x8 af[4], bv[4];
        // ---- phase 1: ks=0, rows 0..63 of wave tile
        PH_DSREAD_BV(rg0);
        PH_DSREAD_AF(0, rg0);
        if (pf) STAGE2(nb, nk, 0);
        PH_BAR();
        PH_MFMA(0);
        PH_BAR();
        // ---- phase 2: ks=0, rows 64..127 (bv reused)
        PH_DSREAD_AF(1, rg0);
        if (pf) STAGE2(nb, nk, 1);
        PH_BAR();
        PH_MFMA(1);
        PH_BAR();
        // ---- phase 3: ks=1, rows 0..63
        PH_DSREAD_BV(rg1);
        PH_DSREAD_AF(0, rg1);
        if (pf) STAGE2(nb, nk, 2);
        PH_BAR();
        PH_MFMA(0);
        PH_BAR();
        // ---- phase 4: ks=1, rows 64..127; certify tile t+1 after MFMA cover
        PH_DSREAD_AF(1, rg1);
        if (pf) STAGE2(nb, nk, 3);
        PH_BAR();
        PH_MFMA(1);
        if (pf) asm volatile("s_waitcnt vmcnt(0)" ::: "memory");
        PH_BAR();
        cur ^= 1;
    }
#undef STAGE2
#undef PH_DSREAD_AF
#undef PH_DSREAD_BV
#undef PH_MFMA
#undef PH_BAR

    const int row0 = bm * 256 + wm * 128;
    const int col0 = bn * 256 + wn * 64;
#pragma unroll
    for (int i = 0; i < 8; i++) {
#pragma unroll
        for (int j = 0; j < 4; j++) {
            const int col = col0 + j * 16 + lm;
            const float bcol = (float)bias[col];
#pragma unroll
            for (int r = 0; r < 4; r++) {
                const int row = row0 + i * 16 + lq * 4 + r;
                C[(size_t)row * N + col] = (__bf16)gelu_exact(acc[i][j][r] + bcol);
            }
        }
    }
}

// ---------------------------------------------------------------------------
// BK=64 GEMM for w2 (bias + resid epilogue, fp32 out). 2x MFMA-per-barrier.
__global__ __launch_bounds__(256, 2) void gemm_bt_k64(
    const __bf16* __restrict__ A, const __bf16* __restrict__ B,
    const __bf16* __restrict__ bias, const float* resid,
    float* C, int M, int N, int K) {
    const int nwg = gridDim.x * gridDim.y;
    int bid = blockIdx.y * gridDim.x + blockIdx.x;
    bid = (bid & 7) * (nwg >> 3) + (bid >> 3);
    const int bm = bid / gridDim.x, bn = bid % gridDim.x;

    const int tid = threadIdx.x;
    const int wave = tid >> 6, lane = tid & 63;
    const int wm = wave & 1, wn = wave >> 1;
    const int lm = lane & 15, lq = lane >> 4;

    __shared__ __align__(16) __bf16 Asmem[2][128 * 64];
    __shared__ __align__(16) __bf16 Bsmem[2][128 * 64];

    f32x4 acc[4][4] = {};

    const __bf16* Abase = A + (size_t)bm * 128 * K;
    const __bf16* Bbase = B + (size_t)bn * 128 * K;

    const int sr = tid >> 3;
    const int sc = (((tid & 7) ^ ((tid >> 3) & 7))) << 3;
    const int wb = wave * 512;

    const __bf16* Ap[4];
    const __bf16* Bp[4];
#pragma unroll
    for (int p = 0; p < 4; p++) {
        Ap[p] = Abase + (size_t)(p * 32 + sr) * K + sc;
        Bp[p] = Bbase + (size_t)(p * 32 + sr) * K + sc;
    }

#define STAGE64(b, kk)                                        \
    do {                                                      \
        _Pragma("unroll")                                     \
        for (int p = 0; p < 4; p++) {                         \
            gload_lds16(Ap[p] + (kk), &Asmem[b][p * 2048 + wb]); \
            gload_lds16(Bp[p] + (kk), &Bsmem[b][p * 2048 + wb]); \
        }                                                     \
    } while (0)

    STAGE64(0, 0);
    __syncthreads();
    int cur = 0;
    for (int k0 = 0; k0 < K; k0 += 64) {
        if (k0 + 64 < K) STAGE64(cur ^ 1, k0 + 64);
        bf16x8 af[2][4], bfv[2][4];
#pragma unroll
        for (int h = 0; h < 2; h++) {
            const int rg = ((h * 4 + lq) ^ (lm & 7)) << 3;
#pragma unroll
            for (int i = 0; i < 4; i++) {
                af[h][i]  = *(const bf16x8*)&Asmem[cur][(wm * 64 + i * 16 + lm) * 64 + rg];
                bfv[h][i] = *(const bf16x8*)&Bsmem[cur][(wn * 64 + i * 16 + lm) * 64 + rg];
            }
        }
#pragma unroll
        for (int h = 0; h < 2; h++)
#pragma unroll
            for (int i = 0; i < 4; i++)
#pragma unroll
                for (int j = 0; j < 4; j++)
                    acc[i][j] = __builtin_amdgcn_mfma_f32_16x16x32_bf16(af[h][i], bfv[h][j], acc[i][j], 0, 0, 0);
        __syncthreads();
        cur ^= 1;
    }
#undef STAGE64

    const int row0 = bm * 128 + wm * 64;
    const int col0 = bn * 128 + wn * 64;
#pragma unroll
    for (int i = 0; i < 4; i++) {
#pragma unroll
        for (int j = 0; j < 4; j++) {
            const int col = col0 + j * 16 + lm;
            const float bcol = (float)bias[col];
#pragma unroll
            for (int r = 0; r < 4; r++) {
                const int row = row0 + i * 16 + lq * 4 + r;
                float v = acc[i][j][r] + bcol;
                v += resid[(size_t)row * N + col];
                C[(size_t)row * N + col] = v;
            }
        }
    }
}

// ---------------------------------------------------------------------------
// KV partials: block (nh, sc, vh) computes KV over 256 s-rows, written
// TRANSPOSED ([v][d]) so attn_out's MFMA B-operand is row-major [N=v, K=d].
__global__ __launch_bounds__(256) void kv_kernel(const __bf16* __restrict__ Kf,
                                                 const __bf16* __restrict__ Vf,
                                                 float* __restrict__ pkv,
                                                 float* __restrict__ pks) {
    const int nh = blockIdx.x, sc = blockIdx.y, vh = blockIdx.z;
    const int n = nh >> 3, h = nh & 7;
    const int tid = threadIdx.x;
    const int tv = tid & 15, td = tid >> 4;
    __shared__ __align__(16) __bf16 Kt[32 * 128];
    __shared__ __align__(16) __bf16 Vt[32 * 64];
    float acc[8][4] = {};
    float ks[8] = {};
    const size_t rowbase = (size_t)n * 4096 + (size_t)sc * 256;
    for (int s0 = 0; s0 < 256; s0 += 32) {
#pragma unroll
        for (int rep = 0; rep < 2; rep++) {
            const int s = tid + rep * 256;
            const int r = s >> 4, cs = (s & 15) * 8;
            const size_t gidx = (rowbase + s0 + r) * 1024 + h * 128 + cs;
            *(bf16x8*)&Kt[r * 128 + cs] = *(const bf16x8*)&Kf[gidx];
        }
        {
            const int r = tid >> 3, cs = (tid & 7) * 8;
            const size_t gidx = (rowbase + s0 + r) * 1024 + h * 128 + vh * 64 + cs;
            *(bf16x8*)&Vt[r * 64 + cs] = *(const bf16x8*)&Vf[gidx];
        }
        __syncthreads();
#pragma unroll 4
        for (int s = 0; s < 32; s++) {
            const bf16x8 k8 = *(const bf16x8*)&Kt[s * 128 + td * 8];
            const bf16x4 v4 = *(const bf16x4*)&Vt[s * 64 + tv * 4];
            float kk[8], vv[4];
#pragma unroll
            for (int i = 0; i < 8; i++) kk[i] = (float)k8[i];
#pragma unroll
            for (int j = 0; j < 4; j++) vv[j] = (float)v4[j];
#pragma unroll
            for (int i = 0; i < 8; i++) {
                ks[i] += kk[i];
#pragma unroll
                for (int j = 0; j < 4; j++) acc[i][j] += kk[i] * vv[j];
            }
        }
        __syncthreads();
    }
    float* dst = pkv + ((size_t)sc * 16 + nh) * 16384;
#pragma unroll
    for (int j = 0; j < 4; j++)
#pragma unroll
        for (int i = 0; i < 8; i++)
            dst[(vh * 64 + tv * 4 + j) * 128 + td * 8 + i] = acc[i][j];
    if (vh == 0 && tv == 0) {
        float* ds2 = pks + ((size_t)sc * 16 + nh) * 128;
#pragma unroll
        for (int i = 0; i < 8; i++) ds2[td * 8 + i] = ks[i];
    }
}

// reduce 16 chunks -> kvbT (bf16, [nh][v][d]) + ksf
__global__ __launch_bounds__(256) void kv_reduce(const float* __restrict__ pkv,
                                                 const float* __restrict__ pks,
                                                 __bf16* __restrict__ kvbT,
                                                 float* __restrict__ ksf) {
    const int idx = blockIdx.x * 256 + threadIdx.x;
    float s = 0.0f;
#pragma unroll
    for (int c = 0; c < 16; c++) s += pkv[(size_t)c * 262144 + idx];
    kvbT[idx] = (__bf16)s;
    if (idx < 2048) {
        float t = 0.0f;
#pragma unroll
        for (int c = 0; c < 16; c++) t += pks[c * 2048 + idx];
        ksf[idx] = t;
    }
}

__global__ __launch_bounds__(256) void z_kernel(const __bf16* __restrict__ Qf,
                                                const float* __restrict__ ksf,
                                                float* __restrict__ zbuf) {
    const int idx = blockIdx.x * 256 + threadIdx.x;
    const int h = idx & 7;
    const size_t row = (size_t)(idx >> 3);
    const __bf16* q = Qf + row * 1024 + h * 128;
    const float* ks = ksf + ((size_t)((row >> 12) * 8 + h)) * 128;
    float s = 0.0f;
    for (int d = 0; d < 128; d += 8) {
        const bf16x8 q8 = *(const bf16x8*)&q[d];
#pragma unroll
        for (int j = 0; j < 8; j++) s += (float)q8[j] * ks[d + j];
    }
    zbuf[idx] = 1.0f / (s + 1e-6f);
}

// attn out + residual via MFMA: xmid = x + (Q @ KV) * z per head.
__global__ __launch_bounds__(256, 3) void attn_out_kernel(
    const __bf16* __restrict__ x, const __bf16* __restrict__ Qf,
    const __bf16* __restrict__ kvbT, const float* __restrict__ zbuf,
    float* __restrict__ xmid) {
    const int nh = blockIdx.x, lc = blockIdx.y;
    const int n = nh >> 3, h = nh & 7;
    const int tid = threadIdx.x;
    const int wv = tid >> 6, lane = tid & 63;
    const int lm = lane & 15, lq = lane >> 4;
    __shared__ __align__(16) __bf16 KVs[128 * 128];
    __shared__ __align__(16) __bf16 Qs[64 * 128];
    __shared__ float Zs[64];
    const __bf16* kv = kvbT + (size_t)nh * 16384;
#pragma unroll
    for (int rep = 0; rep < 8; rep++) {
        const int i = tid + rep * 256;
        const int r = i >> 4, c8 = (i & 15) * 8;
        *(bf16x8*)&KVs[swz128(r, c8)] = *(const bf16x8*)&kv[i * 8];
    }
    const size_t gr0 = (size_t)n * 4096 + (size_t)lc * 64;
#pragma unroll
    for (int rep = 0; rep < 4; rep++) {
        const int s = tid + rep * 256;
        const int r = s >> 4, cs = (s & 15) * 8;
        *(bf16x8*)&Qs[swz128(r, cs)] =
            *(const bf16x8*)&Qf[(gr0 + r) * 1024 + h * 128 + cs];
    }
    if (tid < 64) Zs[tid] = zbuf[(gr0 + tid) * 8 + h];
    __syncthreads();

    const int xmask = (lm & 7) << 3;
    f32x4 acc[4][2] = {};
#pragma unroll
    for (int k0 = 0; k0 < 128; k0 += 32) {
        const int kk = (k0 + lq * 8) ^ xmask;
        bf16x8 af[4], bv[2];
#pragma unroll
        for (int i = 0; i < 4; i++)
            af[i] = *(const bf16x8*)&Qs[(i * 16 + lm) * 128 + kk];
#pragma unroll
        for (int j = 0; j < 2; j++)
            bv[j] = *(const bf16x8*)&KVs[(wv * 32 + j * 16 + lm) * 128 + kk];
#pragma unroll
        for (int i = 0; i < 4; i++)
#pragma unroll
            for (int j = 0; j < 2; j++)
                acc[i][j] = __builtin_amdgcn_mfma_f32_16x16x32_bf16(af[i], bv[j], acc[i][j], 0, 0, 0);
    }
#pragma unroll
    for (int i = 0; i < 4; i++) {
#pragma unroll
        for (int j = 0; j < 2; j++) {
            const int col = wv * 32 + j * 16 + lm;
#pragma unroll
            for (int r = 0; r < 4; r++) {
                const int lr = i * 16 + lq * 4 + r;
                const size_t gi = (gr0 + lr) * 1024 + h * 128 + col;
                xmid[gi] = (float)x[gi] + acc[i][j][r] * Zs[lr];
            }
        }
    }
}

// ---------------------------------------------------------------------------
extern "C" void kernel_launch(void* const* d_in, const int* in_sizes, int n_in,
                              void* d_out, int out_size, void* d_ws, size_t ws_size,
                              hipStream_t stream) {
    float* out = (float*)d_out;   // output is FP32 (reference output dtype)
    char* ws = (char*)d_ws;

    const int nx = 8388608, nw = 1048576, nw1 = 4194304, nb1 = 4096, ng = 1024;
    size_t off = 0;
    __bf16* cx   = (__bf16*)(ws + off); off += (size_t)nx * 2;
    __bf16* cwq  = (__bf16*)(ws + off); off += (size_t)nw * 2;   // cwq/cwk/cwv
    __bf16* cwk  = (__bf16*)(ws + off); off += (size_t)nw * 2;   // contiguous:
    __bf16* cwv  = (__bf16*)(ws + off); off += (size_t)nw * 2;   // [3072,1024]
    __bf16* cw1  = (__bf16*)(ws + off); off += (size_t)nw1 * 2;
    __bf16* cb1  = (__bf16*)(ws + off); off += (size_t)nb1 * 2;
    __bf16* cw2  = (__bf16*)(ws + off); off += (size_t)nw1 * 2;
    __bf16* cb2  = (__bf16*)(ws + off); off += (size_t)ng * 2;   // cb2..cbe2
    __bf16* cg1  = (__bf16*)(ws + off); off += (size_t)ng * 2;   // contiguous
    __bf16* cbe1 = (__bf16*)(ws + off); off += (size_t)ng * 2;   // 5x1024
    __bf16* cg2  = (__bf16*)(ws + off); off += (size_t)ng * 2;
    __bf16* cbe2 = (__bf16*)(ws + off); off += (size_t)ng * 2;
    int* flags = (int*)(ws + off); off += 64;
    (void)cwk; (void)cwv; (void)cg1; (void)cbe1; (void)cg2; (void)cbe2;

    char* PB = ws + off;
    __bf16* x2   = (__bf16*)(PB);                 // LN1 out; later LN2 out (16MB)
    __bf16* Qf   = (__bf16*)(PB + 16777216);      // Q (16MB), QKV contiguous
    __bf16* Kf   = (__bf16*)(PB + 33554432);      // K (16MB)
    __bf16* Vf   = (__bf16*)(PB + 50331648);      // V (16MB)
    float*  pkv  = (float*)(PB + 67108864);       // 16MB, ends 83886080
    float*  pks  = (float*)(PB + 83886080);
    float*  ksf  = (float*)(PB + 84017152);
    float*  zbuf = (float*)(PB + 84025344);
    __bf16* kvbT = (__bf16*)(PB + 84287488);      // ends PB+84,811,776
    __bf16* hbuf = (__bf16*)(PB + 16777216);      // MLP h [8192,4096] bf16 64MB,
                                                  // overlays dead Qf/Kf/Vf/pkv
    float*  xmid = out;                           // attn residual lives in d_out

    // 0. sniff dtype + canonicalize inputs to bf16
    sniff_kernel<<<1, 256, 0, stream>>>((const unsigned short*)d_in[0], flags);
    convert3_kernel<<<3 * nw / 2048, 256, 0, stream>>>(d_in[1], d_in[2], d_in[3], cwq, flags);
    convert_kernel<<<nw1 / 2048, 256, 0, stream>>>(d_in[4], cw1, nw1, flags);
    convert_kernel<<<nw1 / 2048, 256, 0, stream>>>(d_in[6], cw2, nw1, flags);
    Ptr6 sp;
    sp.p[0] = d_in[5];  sp.p[1] = d_in[7];  sp.p[2] = d_in[8];
    sp.p[3] = d_in[9];  sp.p[4] = d_in[10]; sp.p[5] = d_in[11];
    convert_small<<<5, 256, 0, stream>>>(sp, cb1, cb2, flags);

    // 1. fused x-convert + LN1 (writes cx and x2 in one pass over x)
    convert_ln_kernel<<<8192, 256, 0, stream>>>(d_in[0], cg1, cbe1, cx, x2, flags);
    // 2. fused QKV projection: x2[8192,1024] @ [wq;wk;wv]^T -> Q|K|V
    gemm_bt<EP_QKV, __bf16><<<dim3(3072 / 128, 8192 / 128), 256, 0, stream>>>(
        x2, cwq, nullptr, nullptr, Qf, 8192, 3072, 1024);
    // 3. KV + Ksum (v-split: 512 blocks), transposed partials -> kvbT
    kv_kernel<<<dim3(16, 16, 2), 256, 0, stream>>>(Kf, Vf, pkv, pks);
    kv_reduce<<<1024, 256, 0, stream>>>(pkv, pks, kvbT, ksf);
    // 4. Z, attention out (MFMA) + residual -> xmid (= d_out, fp32)
    z_kernel<<<256, 256, 0, stream>>>(Qf, ksf, zbuf);
    attn_out_kernel<<<dim3(16, 64), 256, 0, stream>>>(cx, Qf, kvbT, zbuf, xmid);
    // 5. LN2 + MLP. w1 via 256^2 4-phase pipeline; w2 via BK=64 kernel.
    ln_kernel<float><<<8192, 256, 0, stream>>>(xmid, cg2, cbe2, x2);
    gemm256_gelu<<<dim3(4096 / 256, 8192 / 256), 512, 0, stream>>>(
        x2, cw1, cb1, hbuf, 8192, 4096, 1024);
    gemm_bt_k64<<<dim3(1024 / 128, 8192 / 128), 256, 0, stream>>>(
        hbuf, cw2, cb2, xmid, out, 8192, 1024, 4096);
}